// Round 2
// baseline (472.711 us; speedup 1.0000x reference)
//
#include <hip/hip_runtime.h>
#include <stdint.h>

// ---------------- problem constants ----------------
constexpr int Bn = 64;
constexpr int Nn = 8;
constexpr int Vn = 128000;
constexpr int CH = 32;            // chunks per row
constexpr int CHUNK = Vn / CH;    // 4000 floats
constexpr int F4 = CHUNK / 4;     // 1000 float4 per chunk
constexpr float EPSf = 1e-20f;
constexpr float TINYf = 1.17549435082228751e-38f;  // FLT_MIN, np.finfo(f32).tiny

// ---------------- Threefry-2x32 (JAX-exact) ----------------
struct TFOut { uint32_t a, b; };

__host__ __device__ constexpr TFOut tf2x32(uint32_t k0, uint32_t k1,
                                           uint32_t x0, uint32_t x1) {
  uint32_t k2 = k0 ^ k1 ^ 0x1BD11BDAu;
  x0 += k0; x1 += k1;
#define TFR(r) { x0 += x1; x1 = (uint32_t)((x1 << (r)) | (x1 >> (32 - (r)))); x1 ^= x0; }
  TFR(13) TFR(15) TFR(26) TFR(6)
  x0 += k1; x1 += k2 + 1u;
  TFR(17) TFR(29) TFR(16) TFR(24)
  x0 += k2; x1 += k0 + 2u;
  TFR(13) TFR(15) TFR(26) TFR(6)
  x0 += k0; x1 += k1 + 3u;
  TFR(17) TFR(29) TFR(16) TFR(24)
  x0 += k1; x1 += k2 + 4u;
  TFR(13) TFR(15) TFR(26) TFR(6)
  x0 += k2; x1 += k0 + 5u;
#undef TFR
  return TFOut{x0, x1};
}

// jax.random.key(1) -> key data (0,1).
// threefry_partitionable=True (JAX >= 0.4.36 default):
//   split(key, 3) is FOLD-LIKE: counters (hi,lo) = (0, i) for i in 0..2,
//   new key_i = (out0, out1) of ONE threefry eval.
constexpr TFOut KU = tf2x32(0u, 1u, 0u, 0u);  // ku = split[0]
constexpr TFOut KR = tf2x32(0u, 1u, 0u, 1u);  // kr = split[1]
constexpr TFOut KB_ = tf2x32(0u, 1u, 0u, 2u); // kb = split[2]

// ---------------- device helpers ----------------
__device__ __forceinline__ float jax_u01(uint32_t bits) {
  // (bits >> 9) | 0x3f800000 -> [1,2); minus 1.0 -> [0,1)
  return __uint_as_float((bits >> 9) | 0x3f800000u) - 1.0f;
}

// partitionable random_bits(32): counter (hi,lo) = (0, t); bits = out0 ^ out1
__device__ __forceinline__ uint32_t rbits(uint32_t k0, uint32_t k1, uint32_t t) {
  TFOut o = tf2x32(k0, k1, 0u, t);
  return o.a ^ o.b;
}

__device__ __forceinline__ float gumbel_at(uint32_t k0, uint32_t k1, uint32_t t) {
  float u = jax_u01(rbits(k0, k1, t));
  // uniform(minval=tiny, maxval=1): (1.0f - tiny) rounds to 1.0f -> u*1+tiny, max(tiny,.)
  float uu = fmaxf(TINYf, u + TINYf);
  return -logf(-logf(uu));
}

// order-preserving float->uint map, packed with ~v so max() == JAX first-index argmax
__device__ __forceinline__ unsigned long long packsc(float s, uint32_t v) {
  uint32_t u = __float_as_uint(s);
  uint32_t m = (u & 0x80000000u) ? ~u : (u | 0x80000000u);
  return ((unsigned long long)m << 32) | (unsigned long long)(~v);
}

// accept bit for flat draft position j
__device__ __forceinline__ int accept_bit(int j, const int* __restrict__ ids,
                                          const float* __restrict__ draft,
                                          const float* __restrict__ verify) {
  int b = j >> 3, n = j & 7;
  float u = jax_u01(rbits(KU.a, KU.b, (uint32_t)j));
  int tok = ids[j];
  float p = verify[(size_t)(b * (Nn + 1) + n) * Vn + tok];
  float q = draft[(size_t)(b * Nn + n) * Vn + tok];
  return (u * q < p) ? 1 : 0;
}

// ---------------- kernel A: emitted/accepted + outputs + residual partial sums ----------------
__global__ void __launch_bounds__(256)
KA(const int* __restrict__ ids, const float* __restrict__ draft,
   const float* __restrict__ verify, int* __restrict__ out,
   float* __restrict__ partial, unsigned long long* __restrict__ R) {
  int blk = blockIdx.x;
  int b = blk >> 5, c = blk & 31;
  __shared__ int s_acc[8];
  __shared__ float sred[256];
  if (threadIdx.x < 8) s_acc[threadIdx.x] = accept_bit(b * 8 + threadIdx.x, ids, draft, verify);
  __syncthreads();
  int em = 0;
  while (em < 8 && s_acc[em]) em++;

  if (c == 0 && threadIdx.x == 0) {
    int acc = s_acc[0] + s_acc[1] + s_acc[2] + s_acc[3] + s_acc[4] + s_acc[5] + s_acc[6] + s_acc[7];
    out[Bn * (Nn + 1) + b] = acc;        // accepted_token_num
    out[Bn * (Nn + 1) + Bn + b] = em;    // emitted_token_num
    for (int pos = 0; pos <= Nn; pos++)
      out[b * (Nn + 1) + pos] = (pos < em) ? ids[b * Nn + pos] : -1;  // final slot fixed by KC
    R[b] = 0ull;
  }
  if (em >= Nn) return;  // wave-uniform per block

  const float4* t4 = (const float4*)(verify + (size_t)(b * (Nn + 1) + em) * Vn + c * CHUNK);
  const float4* d4 = (const float4*)(draft + (size_t)(b * Nn + em) * Vn + c * CHUNK);
  float s = 0.0f;
  for (int i = threadIdx.x; i < F4; i += 256) {
    float4 t = t4[i], d = d4[i];
    s += fmaxf(t.x - d.x, 0.0f);
    s += fmaxf(t.y - d.y, 0.0f);
    s += fmaxf(t.z - d.z, 0.0f);
    s += fmaxf(t.w - d.w, 0.0f);
  }
  sred[threadIdx.x] = s;
  __syncthreads();
  for (int st = 128; st > 0; st >>= 1) {
    if (threadIdx.x < st) sred[threadIdx.x] += sred[threadIdx.x + st];
    __syncthreads();
  }
  if (threadIdx.x == 0) partial[blk] = sred[0];
}

// ---------------- kernel B: gumbel-argmax (recovered row OR bonus row) ----------------
__global__ void __launch_bounds__(256)
KB(const int* __restrict__ ids, const float* __restrict__ draft,
   const float* __restrict__ verify, const float* __restrict__ partial,
   unsigned long long* __restrict__ R) {
  int blk = blockIdx.x;
  int b = blk >> 5, c = blk & 31;
  __shared__ int s_acc[8];
  __shared__ unsigned long long smax[256];
  if (threadIdx.x < 8) s_acc[threadIdx.x] = accept_bit(b * 8 + threadIdx.x, ids, draft, verify);
  __syncthreads();
  int em = 0;
  while (em < 8 && s_acc[em]) em++;

  float best = -__builtin_inff();
  uint32_t bestv = 0u;

  if (em < Nn) {
    // deterministic fixed-order sum of the 32 partials (identical every replay)
    float S = 0.0f;
    for (int i = 0; i < CH; i++) S += partial[b * CH + i];
    float Sm = fmaxf(S, EPSf);
    const float4* t4 = (const float4*)(verify + (size_t)(b * (Nn + 1) + em) * Vn + c * CHUNK);
    const float4* d4 = (const float4*)(draft + (size_t)(b * Nn + em) * Vn + c * CHUNK);
    uint32_t trow = (uint32_t)(b * Nn + em) * (uint32_t)Vn;
    for (int i = threadIdx.x; i < F4; i += 256) {
      float4 t = t4[i], d = d4[i];
      uint32_t v0 = (uint32_t)(c * CHUNK + i * 4);
      float tv[4] = {t.x, t.y, t.z, t.w};
      float dv[4] = {d.x, d.y, d.z, d.w};
#pragma unroll
      for (int k = 0; k < 4; k++) {
        float r = fmaxf(tv[k] - dv[k], 0.0f);
        float logit = logf(r / Sm + EPSf);
        float sc = gumbel_at(KR.a, KR.b, trow + v0 + k) + logit;
        if (sc > best) { best = sc; bestv = v0 + k; }  // ascending v => first occurrence
      }
    }
  } else {
    // bonus: argmax over gumbel(kb) + log(verify[b,N,:] + EPS)
    const float4* p4 = (const float4*)(verify + (size_t)(b * (Nn + 1) + Nn) * Vn + c * CHUNK);
    uint32_t trow = (uint32_t)b * (uint32_t)Vn;
    for (int i = threadIdx.x; i < F4; i += 256) {
      float4 p = p4[i];
      uint32_t v0 = (uint32_t)(c * CHUNK + i * 4);
      float pv[4] = {p.x, p.y, p.z, p.w};
#pragma unroll
      for (int k = 0; k < 4; k++) {
        float logit = logf(pv[k] + EPSf);
        float sc = gumbel_at(KB_.a, KB_.b, trow + v0 + k) + logit;
        if (sc > best) { best = sc; bestv = v0 + k; }
      }
    }
  }

  smax[threadIdx.x] = packsc(best, bestv);
  __syncthreads();
  for (int st = 128; st > 0; st >>= 1) {
    if (threadIdx.x < st) {
      unsigned long long o = smax[threadIdx.x + st];
      if (o > smax[threadIdx.x]) smax[threadIdx.x] = o;
    }
    __syncthreads();
  }
  if (threadIdx.x == 0) atomicMax(&R[b], smax[0]);
}

// ---------------- kernel C: write the final token ----------------
__global__ void __launch_bounds__(512)
KC(const int* __restrict__ ids, const float* __restrict__ draft,
   const float* __restrict__ verify, const unsigned long long* __restrict__ R,
   int* __restrict__ out) {
  __shared__ int s_acc[512];
  int j = threadIdx.x;
  s_acc[j] = accept_bit(j, ids, draft, verify);
  __syncthreads();
  if (j < Bn) {
    int em = 0;
    while (em < 8 && s_acc[j * 8 + em]) em++;
    int tok = (int)(~(uint32_t)(R[j] & 0xFFFFFFFFull));
    out[j * (Nn + 1) + em] = tok;
  }
}

// ---------------- launch ----------------
extern "C" void kernel_launch(void* const* d_in, const int* in_sizes, int n_in,
                              void* d_out, int out_size, void* d_ws, size_t ws_size,
                              hipStream_t stream) {
  const int* ids = (const int*)d_in[0];
  const float* draft = (const float*)d_in[1];
  const float* verify = (const float*)d_in[2];
  int* out = (int*)d_out;

  char* w = (char*)d_ws;
  float* partial = (float*)w;                                  // 2048 floats = 8192 B
  unsigned long long* R = (unsigned long long*)(w + 8192);     // 64 * 8 B

  KA<<<dim3(Bn * CH), dim3(256), 0, stream>>>(ids, draft, verify, out, partial, R);
  KB<<<dim3(Bn * CH), dim3(256), 0, stream>>>(ids, draft, verify, partial, R);
  KC<<<dim3(1), dim3(512), 0, stream>>>(ids, draft, verify, R, out);
}